// Round 7
// baseline (1732.224 us; speedup 1.0000x reference)
//
#include <hip/hip_runtime.h>

#define N_NODES 50000
#define N_EDGES 800000
#define IN_DIM 100
#define OUT_DIM 40
#define ROW 50            // 50 dwords = 100 bf16 used per row
#define ROW_PAD 64        // 256 B pitch: one row = 16 lanes x dwordx4
#define CSR_CAP (N_EDGES + N_NODES * 8 + 64)
#define TB 128

typedef unsigned int uint;

// ---- bf16 helpers (packed pair in one dword) ----
__device__ __forceinline__ float bflo(uint u) { return __uint_as_float(u << 16); }
__device__ __forceinline__ float bfhi(uint u) { return __uint_as_float(u & 0xffff0000u); }
__device__ __forceinline__ uint packbf(float a, float b) {
    uint ua = __float_as_uint(a), ub = __float_as_uint(b);
    ua = (ua + 0x7fffu + ((ua >> 16) & 1u)) >> 16;      // RNE
    ub = (ub + 0x7fffu + ((ub >> 16) & 1u)) >> 16;
    return ua | (ub << 16);
}

// ---- software grid barrier (device-scope; all blocks guaranteed resident) ----
__device__ __forceinline__ void gridbar(int* cnt, int nblk) {
    __syncthreads();
    if (threadIdx.x == 0) {
        __threadfence();
        __hip_atomic_fetch_add(cnt, 1, __ATOMIC_ACQ_REL, __HIP_MEMORY_SCOPE_AGENT);
        while (__hip_atomic_load(cnt, __ATOMIC_ACQUIRE, __HIP_MEMORY_SCOPE_AGENT) < nblk)
            __builtin_amdgcn_s_sleep(2);
        __threadfence();
    }
    __syncthreads();
}

// ---- one SGC hop: out[n] = bf16(scale[n] * sum_{s in N(n)} H[s]), wave/node ----
__device__ __forceinline__ void hop(const uint4* __restrict__ H4,
                                    const int* __restrict__ rowptr,
                                    const int* __restrict__ csr,
                                    const float* __restrict__ scale,
                                    uint4* __restrict__ out4,
                                    int gwid, int gwaves, int lane) {
    const int q = lane >> 4, ql = lane & 15;
    for (int n = gwid; n < N_NODES; n += gwaves) {
        const int beg = rowptr[n], end = rowptr[n + 1];   // multiple-of-8 span
        float ax0 = 0.f, ax1 = 0.f, ax2 = 0.f, ax3 = 0.f;
        float ay0 = 0.f, ay1 = 0.f, ay2 = 0.f, ay3 = 0.f;
        for (int j = beg; j < end; j += 8) {
            int s0 = csr[j + q];
            int s1 = csr[j + 4 + q];
            uint4 u0 = H4[(size_t)s0 * 16 + ql];
            uint4 u1 = H4[(size_t)s1 * 16 + ql];
            ax0 += bflo(u0.x); ay0 += bfhi(u0.x);
            ax1 += bflo(u0.y); ay1 += bfhi(u0.y);
            ax2 += bflo(u0.z); ay2 += bfhi(u0.z);
            ax3 += bflo(u0.w); ay3 += bfhi(u0.w);
            ax0 += bflo(u1.x); ay0 += bfhi(u1.x);
            ax1 += bflo(u1.y); ay1 += bfhi(u1.y);
            ax2 += bflo(u1.z); ay2 += bfhi(u1.z);
            ax3 += bflo(u1.w); ay3 += bfhi(u1.w);
        }
        ax0 += __shfl_xor(ax0, 16); ax1 += __shfl_xor(ax1, 16);
        ax2 += __shfl_xor(ax2, 16); ax3 += __shfl_xor(ax3, 16);
        ay0 += __shfl_xor(ay0, 16); ay1 += __shfl_xor(ay1, 16);
        ay2 += __shfl_xor(ay2, 16); ay3 += __shfl_xor(ay3, 16);
        ax0 += __shfl_xor(ax0, 32); ax1 += __shfl_xor(ax1, 32);
        ax2 += __shfl_xor(ax2, 32); ax3 += __shfl_xor(ax3, 32);
        ay0 += __shfl_xor(ay0, 32); ay1 += __shfl_xor(ay1, 32);
        ay2 += __shfl_xor(ay2, 32); ay3 += __shfl_xor(ay3, 32);
        if (q == 0) {
            float sc = scale[n];
            uint4 o;
            o.x = packbf(ax0 * sc, ay0 * sc);
            o.y = packbf(ax1 * sc, ay1 * sc);
            o.z = packbf(ax2 * sc, ay2 * sc);
            o.w = packbf(ax3 * sc, ay3 * sc);
            out4[(size_t)n * 16 + ql] = o;
        }
    }
}

// LDS budget: union max = fin (160 + 16000 = 16160 B) <= 16384 B @ 10 blocks/CU.
__global__ __launch_bounds__(TB, 5) void mega_kernel(
    const float* __restrict__ feat, const float* __restrict__ W,
    const float* __restrict__ b, const int* __restrict__ src,
    const int* __restrict__ dst,
    int* deg, float* colsum, float* colsq, int* barcnt,
    int* eoff, int* rowptr, float* norm, float* norm2,
    int* blocksum, int* csr,
    uint* fs, uint* bufA, uint* bufB,
    float* out, int G) {
    __shared__ union {
        int wtot[2];                                          // P2a
        struct { float ssum[IN_DIM]; float ssq[IN_DIM]; } cs; // P7
        struct { float sb[OUT_DIM]; float w[IN_DIM * OUT_DIM]; } fin; // P8
    } sh;

    const int t = threadIdx.x;
    const int gid = blockIdx.x * TB + t;
    const int gstride = G * TB;
    const int lane = t & 63;
    const int gwid = blockIdx.x * 2 + (t >> 6);
    const int gwaves = G * 2;

    // ---- P1: in-degree + per-edge slot ----
    for (int e = gid; e < N_EDGES; e += gstride)
        eoff[e] = atomicAdd(&deg[dst[e]], 1);
    gridbar(&barcnt[0], G);

    // ---- P2a: per-chunk scan of 8-aligned degrees (98 chunks of 512) + norms ----
    if (blockIdx.x < 98) {
        int i0 = blockIdx.x * 512 + t * 4;
        int d0 = (i0     < N_NODES) ? deg[i0    ] : 0;
        int d1 = (i0 + 1 < N_NODES) ? deg[i0 + 1] : 0;
        int d2 = (i0 + 2 < N_NODES) ? deg[i0 + 2] : 0;
        int d3 = (i0 + 3 < N_NODES) ? deg[i0 + 3] : 0;
        int a0 = (d0 + 7) & ~7, a1 = (d1 + 7) & ~7, a2 = (d2 + 7) & ~7, a3 = (d3 + 7) & ~7;
        int s = a0 + a1 + a2 + a3;
        int incl = s;
#pragma unroll
        for (int off = 1; off < 64; off <<= 1) {
            int v = __shfl_up(incl, off);
            if (lane >= off) incl += v;
        }
        if (lane == 63) sh.wtot[t >> 6] = incl;
        __syncthreads();
        int base = (t >= 64) ? sh.wtot[0] : 0;
        int excl = base + incl - s;
        if (i0     < N_NODES) { rowptr[i0    ] = excl;                float n1 = 1.0f / sqrtf((float)max(d0, 1)); norm[i0    ] = n1; norm2[i0    ] = n1 * n1; }
        if (i0 + 1 < N_NODES) { rowptr[i0 + 1] = excl + a0;           float n1 = 1.0f / sqrtf((float)max(d1, 1)); norm[i0 + 1] = n1; norm2[i0 + 1] = n1 * n1; }
        if (i0 + 2 < N_NODES) { rowptr[i0 + 2] = excl + a0 + a1;      float n1 = 1.0f / sqrtf((float)max(d2, 1)); norm[i0 + 2] = n1; norm2[i0 + 2] = n1 * n1; }
        if (i0 + 3 < N_NODES) { rowptr[i0 + 3] = excl + a0 + a1 + a2; float n1 = 1.0f / sqrtf((float)max(d3, 1)); norm[i0 + 3] = n1; norm2[i0 + 3] = n1 * n1; }
        if (t == 127) blocksum[blockIdx.x] = base + incl;
    }
    gridbar(&barcnt[1], G);

    // ---- P2b: apply block offsets, fill CSR pad slots, write rowptr[N] ----
    if (blockIdx.x < 98) {
        int bb = blockIdx.x;
        int boff = 0, tot = 0;
        for (int j = 0; j < 98; ++j) {
            int v = blocksum[j];
            tot += v;
            boff += (j < bb) ? v : 0;
        }
        int i0 = bb * 512 + t * 4;
#pragma unroll
        for (int k = 0; k < 4; ++k) {
            int i = i0 + k;
            if (i < N_NODES) {
                int rp = rowptr[i] + boff;
                rowptr[i] = rp;
                int d = deg[i], da = (d + 7) & ~7;
                for (int p = d; p < da; ++p) csr[rp + p] = N_NODES;  // dummy -> zero row
            }
        }
        if (bb == 0 && t == 0) rowptr[N_NODES] = tot;
    }
    gridbar(&barcnt[2], G);

    // ---- P3: csr_fill + prescale + zero pad rows (fused, disjoint task ranges) ----
    {
        const int T1 = N_EDGES, T2 = N_NODES * 16, TT = T1 + T2 + 48;
        for (int task = gid; task < TT; task += gstride) {
            if (task < T1) {
                csr[rowptr[dst[task]] + eoff[task]] = src[task];
            } else if (task < T1 + T2) {
                int qq = task - T1;
                int n = qq >> 4, ql = qq & 15;
                float nm = norm[n];
                uint4 o = make_uint4(0u, 0u, 0u, 0u);
                const float4* fr = (const float4*)(feat + (size_t)n * IN_DIM);
                if (ql < 12) {
                    float4 x = fr[2 * ql], y = fr[2 * ql + 1];
                    o.x = packbf(x.x * nm, x.y * nm); o.y = packbf(x.z * nm, x.w * nm);
                    o.z = packbf(y.x * nm, y.y * nm); o.w = packbf(y.z * nm, y.w * nm);
                } else if (ql == 12) {
                    float4 x = fr[24];
                    o.x = packbf(x.x * nm, x.y * nm); o.y = packbf(x.z * nm, x.w * nm);
                }
                ((uint4*)fs)[qq] = o;
            } else {
                int k = task - T1 - T2;   // 0..47: zero pad row (index N_NODES) of each buf
                uint4 z = make_uint4(0u, 0u, 0u, 0u);
                uint4* dp = (k < 16) ? (uint4*)fs : (k < 32) ? (uint4*)bufA : (uint4*)bufB;
                dp[(size_t)N_NODES * 16 + (k & 15)] = z;
            }
        }
    }
    gridbar(&barcnt[3], G);

    // ---- P4..P6: three hops ----
    hop((const uint4*)fs,   rowptr, csr, norm2, (uint4*)bufA, gwid, gwaves, lane);
    gridbar(&barcnt[4], G);
    hop((const uint4*)bufA, rowptr, csr, norm2, (uint4*)bufB, gwid, gwaves, lane);
    gridbar(&barcnt[5], G);
    hop((const uint4*)bufB, rowptr, csr, norm,  (uint4*)bufA, gwid, gwaves, lane);
    gridbar(&barcnt[6], G);

    // ---- P7: column stats (wave/node; lane = fixed dword slot) ----
    if (t < IN_DIM) { sh.cs.ssum[t] = 0.f; sh.cs.ssq[t] = 0.f; }
    __syncthreads();
    {
        float sA = 0.f, sB = 0.f, qA = 0.f, qB = 0.f;
        for (int n = gwid; n < N_NODES; n += gwaves) {
            uint u = bufA[(size_t)n * ROW_PAD + lane];   // lanes 50..63 read zero pads
            float x = bflo(u), y = bfhi(u);
            sA += x; sB += y; qA += x * x; qB += y * y;
        }
        if (lane < ROW) {
            atomicAdd(&sh.cs.ssum[2 * lane],     sA);
            atomicAdd(&sh.cs.ssum[2 * lane + 1], sB);
            atomicAdd(&sh.cs.ssq[2 * lane],      qA);
            atomicAdd(&sh.cs.ssq[2 * lane + 1],  qB);
        }
    }
    __syncthreads();
    if (t < IN_DIM) {
        atomicAdd(&colsum[t], sh.cs.ssum[t]);
        atomicAdd(&colsq[t],  sh.cs.ssq[t]);
    }
    gridbar(&barcnt[7], G);

    // ---- P8: final linear; each block rebuilds W' = W/sigma, b' locally ----
    {
        const float Nf = (float)N_NODES;
        for (int i = t; i < IN_DIM * OUT_DIM; i += TB) {
            int f = i / OUT_DIM, o = i - f * OUT_DIM;
            float m = colsum[f] / Nf;
            float var = fmaxf((colsq[f] - Nf * m * m) / (Nf - 1.0f), 1e-20f);
            sh.fin.w[f * OUT_DIM + o] = W[o * IN_DIM + f] * rsqrtf(var);
        }
        if (t < OUT_DIM) {
            float acc = b[t];
            for (int f = 0; f < IN_DIM; ++f) {
                float m = colsum[f] / Nf;
                float var = fmaxf((colsq[f] - Nf * m * m) / (Nf - 1.0f), 1e-20f);
                acc -= m * W[t * IN_DIM + f] * rsqrtf(var);
            }
            sh.fin.sb[t] = acc;
        }
        __syncthreads();
        for (int task = gid; task < N_NODES * 10; task += gstride) {
            int n = task / 10;
            int og = (task - n * 10) * 4;
            const uint4* hr = (const uint4*)bufA + (size_t)n * 16;
            float a0 = sh.fin.sb[og], a1 = sh.fin.sb[og + 1];
            float a2 = sh.fin.sb[og + 2], a3 = sh.fin.sb[og + 3];
#pragma unroll
            for (int r = 0; r < 12; ++r) {
                uint4 u = hr[r];
                int f = r * 8;
                float v0 = bflo(u.x), v1 = bfhi(u.x), v2 = bflo(u.y), v3 = bfhi(u.y);
                float v4 = bflo(u.z), v5 = bfhi(u.z), v6 = bflo(u.w), v7 = bfhi(u.w);
                const float* w0 = &sh.fin.w[(f + 0) * OUT_DIM + og];
                const float* w1 = &sh.fin.w[(f + 1) * OUT_DIM + og];
                const float* w2 = &sh.fin.w[(f + 2) * OUT_DIM + og];
                const float* w3 = &sh.fin.w[(f + 3) * OUT_DIM + og];
                const float* w4 = &sh.fin.w[(f + 4) * OUT_DIM + og];
                const float* w5 = &sh.fin.w[(f + 5) * OUT_DIM + og];
                const float* w6 = &sh.fin.w[(f + 6) * OUT_DIM + og];
                const float* w7 = &sh.fin.w[(f + 7) * OUT_DIM + og];
                a0 += v0 * w0[0] + v1 * w1[0] + v2 * w2[0] + v3 * w3[0]
                    + v4 * w4[0] + v5 * w5[0] + v6 * w6[0] + v7 * w7[0];
                a1 += v0 * w0[1] + v1 * w1[1] + v2 * w2[1] + v3 * w3[1]
                    + v4 * w4[1] + v5 * w5[1] + v6 * w6[1] + v7 * w7[1];
                a2 += v0 * w0[2] + v1 * w1[2] + v2 * w2[2] + v3 * w3[2]
                    + v4 * w4[2] + v5 * w5[2] + v6 * w6[2] + v7 * w7[2];
                a3 += v0 * w0[3] + v1 * w1[3] + v2 * w2[3] + v3 * w3[3]
                    + v4 * w4[3] + v5 * w5[3] + v6 * w6[3] + v7 * w7[3];
            }
            {   // features 96..99 (dwords 48,49; 50,51 are zero pads)
                uint4 u = hr[12];
                float v0 = bflo(u.x), v1 = bfhi(u.x), v2 = bflo(u.y), v3 = bfhi(u.y);
                const float* w0 = &sh.fin.w[96 * OUT_DIM + og];
                const float* w1 = &sh.fin.w[97 * OUT_DIM + og];
                const float* w2 = &sh.fin.w[98 * OUT_DIM + og];
                const float* w3 = &sh.fin.w[99 * OUT_DIM + og];
                a0 += v0 * w0[0] + v1 * w1[0] + v2 * w2[0] + v3 * w3[0];
                a1 += v0 * w0[1] + v1 * w1[1] + v2 * w2[1] + v3 * w3[1];
                a2 += v0 * w0[2] + v1 * w1[2] + v2 * w2[2] + v3 * w3[2];
                a3 += v0 * w0[3] + v1 * w1[3] + v2 * w2[3] + v3 * w3[3];
            }
            float4 o4 = make_float4(a0, a1, a2, a3);
            *((float4*)(out + (size_t)n * OUT_DIM + og)) = o4;
        }
    }
}

extern "C" void kernel_launch(void* const* d_in, const int* in_sizes, int n_in,
                              void* d_out, int out_size, void* d_ws, size_t ws_size,
                              hipStream_t stream) {
    const float* feat = (const float*)d_in[0];   // [50000,100]
    const float* W    = (const float*)d_in[1];   // [40,100]
    const float* b    = (const float*)d_in[2];   // [40]
    const int*   src  = (const int*)d_in[3];     // [800000]
    const int*   dst  = (const int*)d_in[4];     // [800000]
    float* out = (float*)d_out;                  // [50000,40]

    char* w = (char*)d_ws;
    int*   deg      = (int*)w;    w += N_NODES * 4;
    float* colsum   = (float*)w;  w += 128 * 4;
    float* colsq    = (float*)w;  w += 128 * 4;
    int*   barcnt   = (int*)w;    w += 16 * 4;
    // ---- end of memset-zero region: (N_NODES + 256 + 16) ints ----
    int*   eoff     = (int*)w;    w += N_EDGES * 4;
    int*   rowptr   = (int*)w;    w += 50004 * 4;
    float* norm     = (float*)w;  w += N_NODES * 4;
    float* norm2    = (float*)w;  w += N_NODES * 4;
    int*   blocksum = (int*)w;    w += 128 * 4;
    int*   csr      = (int*)w;    w += CSR_CAP * 4;
    w = (char*)(((size_t)w + 255) & ~(size_t)255);   // 256B-align row buffers
    const size_t HB = (size_t)(N_NODES + 1) * ROW_PAD * 4;
    uint*  fs       = (uint*)w;   w += HB;
    uint*  bufA     = (uint*)w;   w += HB;
    uint*  bufB     = (uint*)w;   w += HB;

    // 1. zero {deg, colsum, colsq, barrier counters} in one memset node
    hipMemsetAsync(d_ws, 0, (size_t)(N_NODES + 256 + 16) * 4, stream);

    // 2. persistent mega-kernel; grid sized to guaranteed co-residency
    int maxb = 0;
    hipOccupancyMaxActiveBlocksPerMultiprocessor(&maxb, mega_kernel, TB, 0);
    int G = maxb * 256;          // 256 CUs
    if (G > 2560) G = 2560;      // cap at launch_bounds-implied capacity
    if (G < 256) G = 256;        // fallback: 1 block/CU always fits
    mega_kernel<<<G, TB, 0, stream>>>(feat, W, b, src, dst,
                                      deg, colsum, colsq, barcnt,
                                      eoff, rowptr, norm, norm2,
                                      blocksum, csr, fs, bufA, bufB,
                                      out, G);
}

// Round 8
// 270.819 us; speedup vs baseline: 6.3962x; 6.3962x over previous
//
#include <hip/hip_runtime.h>

#define N_NODES 50000
#define N_EDGES 800000
#define IN_DIM 100
#define OUT_DIM 40
#define ROW 50            // 50 dwords = 100 bf16 per node row (used)
#define ROW_PAD 64        // padded pitch: 256 B -> one row = 16 lanes x dwordx4
#define SCAN_B 512
#define NSCAN_BLK ((N_NODES + SCAN_B - 1) / SCAN_B)   // 98
#define CSR_CAP (N_EDGES + N_NODES * 8 + 64)          // aligned-degree worst case

typedef unsigned int uint;

// ---- bf16 helpers (packed pair in one dword) ----
__device__ __forceinline__ float bflo(uint u) { return __uint_as_float(u << 16); }
__device__ __forceinline__ float bfhi(uint u) { return __uint_as_float(u & 0xffff0000u); }
__device__ __forceinline__ uint packbf(float a, float b) {
    uint ua = __float_as_uint(a), ub = __float_as_uint(b);
    ua = (ua + 0x7fffu + ((ua >> 16) & 1u)) >> 16;      // RNE
    ub = (ub + 0x7fffu + ((ub >> 16) & 1u)) >> 16;
    return ua | (ub << 16);
}

// ---------------- in-degree; keep returned old count as the edge's slot ----------------
__global__ void deg_kernel(const int* __restrict__ dst, int* __restrict__ deg,
                           int* __restrict__ eoff) {
    int e = blockIdx.x * blockDim.x + threadIdx.x;
    if (e < N_EDGES) eoff[e] = atomicAdd(&deg[dst[e]], 1);
}

// ---------------- scan phase 1: scan ALIGNED degrees ((d+7)&~7), emit norms ----
__global__ __launch_bounds__(SCAN_B) void scan1_kernel(const int* __restrict__ deg,
                                                       int* __restrict__ rowptr,
                                                       float* __restrict__ norm,
                                                       float* __restrict__ norm2,
                                                       int* __restrict__ blocksum) {
    int i = blockIdx.x * SCAN_B + threadIdx.x;
    int lane = threadIdx.x & 63, wid = threadIdx.x >> 6;
    int d = (i < N_NODES) ? deg[i] : 0;
    int da = (d + 7) & ~7;          // pad each node's edge list to multiple of 8
    int v = da;
#pragma unroll
    for (int off = 1; off < 64; off <<= 1) {
        int t = __shfl_up(v, off);
        if (lane >= off) v += t;
    }
    __shared__ int wsum[8];
    if (lane == 63) wsum[wid] = v;
    __syncthreads();
    if (threadIdx.x < 8) {
        int w = wsum[threadIdx.x];
#pragma unroll
        for (int off = 1; off < 8; off <<= 1) {
            int t = __shfl_up(w, off);
            if (lane >= off) w += t;
        }
        wsum[threadIdx.x] = w;
    }
    __syncthreads();
    int woff = wid ? wsum[wid - 1] : 0;
    int incl = woff + v;
    if (i < N_NODES) {
        rowptr[i] = incl - da;      // block-local exclusive
        float n1 = 1.0f / sqrtf((float)max(d, 1));
        norm[i] = n1;
        norm2[i] = n1 * n1;
    }
    if (threadIdx.x == SCAN_B - 1) blocksum[blockIdx.x] = incl;
}

// ---------------- scan phases 2+3 fused: offsets + CSR pad slots ----------------
__global__ __launch_bounds__(SCAN_B) void scan23_kernel(int* __restrict__ rowptr,
                                                        const int* __restrict__ blocksum,
                                                        const int* __restrict__ deg,
                                                        int* __restrict__ csr) {
    __shared__ int s_boff, s_tot;
    int t = threadIdx.x, bb = blockIdx.x;
    if (t == 0) {
        int boff = 0, tot = 0;
        for (int j = 0; j < NSCAN_BLK; ++j) {
            int v = blocksum[j];
            tot += v;
            if (j < bb) boff += v;
        }
        s_boff = boff;
        s_tot = tot;
    }
    __syncthreads();
    int i = bb * SCAN_B + t;
    if (i < N_NODES) {
        int rp = rowptr[i] + s_boff;
        rowptr[i] = rp;
        int d = deg[i], da = (d + 7) & ~7;
        for (int k = d; k < da; ++k) csr[rp + k] = N_NODES;   // dummy -> zero row
    }
    if (bb == 0 && t == 0) rowptr[N_NODES] = s_tot;
}

// ---------------- fused: CSR scatter + prescale + zero pad rows ----------------
__global__ __launch_bounds__(256) void fill_kernel(const int* __restrict__ src,
                                                   const int* __restrict__ dst,
                                                   const int* __restrict__ rowptr,
                                                   const int* __restrict__ eoff,
                                                   int* __restrict__ csr,
                                                   const float* __restrict__ feat,
                                                   const float* __restrict__ norm,
                                                   uint4* __restrict__ fs4,
                                                   uint4* __restrict__ bufA4,
                                                   uint4* __restrict__ bufB4) {
    const int T1 = N_EDGES, T2 = N_NODES * 16;
    int task = blockIdx.x * 256 + threadIdx.x;
    if (task < T1) {
        csr[rowptr[dst[task]] + eoff[task]] = src[task];
    } else if (task < T1 + T2) {
        int qq = task - T1;
        int n = qq >> 4, ql = qq & 15;
        float nm = norm[n];
        uint4 o = make_uint4(0u, 0u, 0u, 0u);
        const float4* fr = (const float4*)(feat + (size_t)n * IN_DIM);
        if (ql < 12) {
            float4 a = fr[2 * ql], b2 = fr[2 * ql + 1];
            o.x = packbf(a.x * nm, a.y * nm);  o.y = packbf(a.z * nm, a.w * nm);
            o.z = packbf(b2.x * nm, b2.y * nm); o.w = packbf(b2.z * nm, b2.w * nm);
        } else if (ql == 12) {
            float4 a = fr[24];                 // features 96..99
            o.x = packbf(a.x * nm, a.y * nm);  o.y = packbf(a.z * nm, a.w * nm);
        }
        fs4[qq] = o;
    } else if (task < T1 + T2 + 48) {
        int k = task - T1 - T2;   // zero pad row (index N_NODES) of each buffer
        uint4 z = make_uint4(0u, 0u, 0u, 0u);
        uint4* dp = (k < 16) ? fs4 : (k < 32) ? bufA4 : bufB4;
        dp[(size_t)N_NODES * 16 + (k & 15)] = z;
    }
}

// ---------------- SGC hop: out[n] = bf16( scale[n] * sum_{s in N(n)} H[s] ) ----
// One wave per node (2 nodes / 128-thr block). Quarter-wave gather: each
// 16-lane quarter loads one full 256B row as dwordx4 -> 4 edges PER
// INSTRUCTION. Edge lists 8-aligned, dummies -> zero row: no bounds logic.
__global__ __launch_bounds__(128) void spmm_kernel(const uint4* __restrict__ H4,
                                                   const int* __restrict__ rowptr,
                                                   const int* __restrict__ csr,
                                                   const float* __restrict__ scale,
                                                   uint4* __restrict__ out4) {
    const int n = blockIdx.x * 2 + (threadIdx.x >> 6);
    const int l = threadIdx.x & 63;
    const int q = l >> 4;          // quarter 0..3
    const int ql = l & 15;         // lane within quarter
    const int beg = rowptr[n], end = rowptr[n + 1];   // multiple-of-8 span
    float ax0 = 0.f, ax1 = 0.f, ax2 = 0.f, ax3 = 0.f;
    float ay0 = 0.f, ay1 = 0.f, ay2 = 0.f, ay3 = 0.f;
#pragma unroll 2
    for (int j = beg; j < end; j += 8) {
        int s0 = csr[j + q];
        int s1 = csr[j + 4 + q];
        uint4 u0 = H4[(size_t)s0 * 16 + ql];
        uint4 u1 = H4[(size_t)s1 * 16 + ql];
        ax0 += bflo(u0.x); ay0 += bfhi(u0.x);
        ax1 += bflo(u0.y); ay1 += bfhi(u0.y);
        ax2 += bflo(u0.z); ay2 += bfhi(u0.z);
        ax3 += bflo(u0.w); ay3 += bfhi(u0.w);
        ax0 += bflo(u1.x); ay0 += bfhi(u1.x);
        ax1 += bflo(u1.y); ay1 += bfhi(u1.y);
        ax2 += bflo(u1.z); ay2 += bfhi(u1.z);
        ax3 += bflo(u1.w); ay3 += bfhi(u1.w);
    }
    // reduce the 4 quarters
    ax0 += __shfl_xor(ax0, 16); ax1 += __shfl_xor(ax1, 16);
    ax2 += __shfl_xor(ax2, 16); ax3 += __shfl_xor(ax3, 16);
    ay0 += __shfl_xor(ay0, 16); ay1 += __shfl_xor(ay1, 16);
    ay2 += __shfl_xor(ay2, 16); ay3 += __shfl_xor(ay3, 16);
    ax0 += __shfl_xor(ax0, 32); ax1 += __shfl_xor(ax1, 32);
    ax2 += __shfl_xor(ax2, 32); ax3 += __shfl_xor(ax3, 32);
    ay0 += __shfl_xor(ay0, 32); ay1 += __shfl_xor(ay1, 32);
    ay2 += __shfl_xor(ay2, 32); ay3 += __shfl_xor(ay3, 32);
    if (q == 0) {
        float sc = scale[n];
        uint4 o;
        o.x = packbf(ax0 * sc, ay0 * sc);
        o.y = packbf(ax1 * sc, ay1 * sc);
        o.z = packbf(ax2 * sc, ay2 * sc);
        o.w = packbf(ax3 * sc, ay3 * sc);
        out4[(size_t)n * 16 + ql] = o;   // full row incl. zero pads
    }
}

// ---------------- per-feature sum/sumsq over padded bf16 h3 ----------------
#define CS_BLOCKS 625
#define CS_THREADS 256   // stride 160000 (mult of 64) -> fixed dword-slot per thread
__global__ __launch_bounds__(CS_THREADS) void col_stats_kernel(const uint* __restrict__ h,
                                                               float* __restrict__ colsum,
                                                               float* __restrict__ colsq) {
    int gtid = blockIdx.x * CS_THREADS + threadIdx.x;
    const int stride = CS_BLOCKS * CS_THREADS;
    const int total = N_NODES * ROW_PAD;
    float s0 = 0.f, s1 = 0.f, q0 = 0.f, q1 = 0.f;
    for (int i = gtid; i < total; i += stride) {   // pads are zero, harmless
        uint u = h[i];
        float a = bflo(u), b = bfhi(u);
        s0 += a; s1 += b; q0 += a * a; q1 += b * b;
    }
    __shared__ float ssum[IN_DIM], ssq[IN_DIM];
    if (threadIdx.x < IN_DIM) { ssum[threadIdx.x] = 0.f; ssq[threadIdx.x] = 0.f; }
    __syncthreads();
    int p = gtid & 63;
    if (p < ROW) {
        atomicAdd(&ssum[2 * p], s0);
        atomicAdd(&ssum[2 * p + 1], s1);
        atomicAdd(&ssq[2 * p], q0);
        atomicAdd(&ssq[2 * p + 1], q1);
    }
    __syncthreads();
    if (threadIdx.x < IN_DIM) {
        atomicAdd(&colsum[threadIdx.x], ssum[threadIdx.x]);
        atomicAdd(&colsq[threadIdx.x], ssq[threadIdx.x]);
    }
}

// ---------------- final linear; rebuilds W'=W/sigma, b' in LDS (prep fused) ----
// sW padded to 104 features (rows 100..103 = 0) so the 13th uint4 of each row
// (dwords 48..51, features 96..103) needs no special-casing.
__global__ __launch_bounds__(256) void final_kernel(const uint4* __restrict__ h4,
                                                    const float* __restrict__ colsum,
                                                    const float* __restrict__ colsq,
                                                    const float* __restrict__ W,
                                                    const float* __restrict__ b,
                                                    float* __restrict__ out) {
    __shared__ float sW[104 * OUT_DIM];   // 16.25 KB
    __shared__ float sb[OUT_DIM];
    const float Nf = (float)N_NODES;
    for (int i = threadIdx.x; i < 104 * OUT_DIM; i += 256) {
        int f = i / OUT_DIM, o = i - f * OUT_DIM;
        float wv = 0.f;
        if (f < IN_DIM) {
            float m = colsum[f] / Nf;
            float var = fmaxf((colsq[f] - Nf * m * m) / (Nf - 1.0f), 1e-20f);
            wv = W[o * IN_DIM + f] * rsqrtf(var);
        }
        sW[i] = wv;
    }
    if (threadIdx.x < OUT_DIM) {
        float acc = b[threadIdx.x];
        for (int f = 0; f < IN_DIM; ++f) {
            float m = colsum[f] / Nf;
            float var = fmaxf((colsq[f] - Nf * m * m) / (Nf - 1.0f), 1e-20f);
            acc -= m * W[threadIdx.x * IN_DIM + f] * rsqrtf(var);
        }
        sb[threadIdx.x] = acc;
    }
    __syncthreads();
    int t = blockIdx.x * 256 + threadIdx.x;
    if (t >= N_NODES * 10) return;
    int n = t / 10;
    int og = (t - n * 10) * 4;            // output group of 4
    const uint4* hr = h4 + (size_t)n * 16;
    float a0 = sb[og], a1 = sb[og + 1], a2 = sb[og + 2], a3 = sb[og + 3];
#pragma unroll
    for (int r = 0; r < 13; ++r) {        // dwords 0..51 (50,51 are zero pads)
        uint4 u = hr[r];
        int f = r * 8;
        float v0 = bflo(u.x), v1 = bfhi(u.x), v2 = bflo(u.y), v3 = bfhi(u.y);
        float v4 = bflo(u.z), v5 = bfhi(u.z), v6 = bflo(u.w), v7 = bfhi(u.w);
        const float* w0 = &sW[(f + 0) * OUT_DIM + og];
        const float* w1 = &sW[(f + 1) * OUT_DIM + og];
        const float* w2 = &sW[(f + 2) * OUT_DIM + og];
        const float* w3 = &sW[(f + 3) * OUT_DIM + og];
        const float* w4 = &sW[(f + 4) * OUT_DIM + og];
        const float* w5 = &sW[(f + 5) * OUT_DIM + og];
        const float* w6 = &sW[(f + 6) * OUT_DIM + og];
        const float* w7 = &sW[(f + 7) * OUT_DIM + og];
        a0 += v0 * w0[0] + v1 * w1[0] + v2 * w2[0] + v3 * w3[0]
            + v4 * w4[0] + v5 * w5[0] + v6 * w6[0] + v7 * w7[0];
        a1 += v0 * w0[1] + v1 * w1[1] + v2 * w2[1] + v3 * w3[1]
            + v4 * w4[1] + v5 * w5[1] + v6 * w6[1] + v7 * w7[1];
        a2 += v0 * w0[2] + v1 * w1[2] + v2 * w2[2] + v3 * w3[2]
            + v4 * w4[2] + v5 * w5[2] + v6 * w6[2] + v7 * w7[2];
        a3 += v0 * w0[3] + v1 * w1[3] + v2 * w2[3] + v3 * w3[3]
            + v4 * w4[3] + v5 * w5[3] + v6 * w6[3] + v7 * w7[3];
    }
    float4 o = make_float4(a0, a1, a2, a3);
    *((float4*)(out + (size_t)n * OUT_DIM + og)) = o;
}

extern "C" void kernel_launch(void* const* d_in, const int* in_sizes, int n_in,
                              void* d_out, int out_size, void* d_ws, size_t ws_size,
                              hipStream_t stream) {
    const float* feat = (const float*)d_in[0];   // [50000,100]
    const float* W    = (const float*)d_in[1];   // [40,100]
    const float* b    = (const float*)d_in[2];   // [40]
    const int*   src  = (const int*)d_in[3];     // [800000]
    const int*   dst  = (const int*)d_in[4];     // [800000]
    float* out = (float*)d_out;                  // [50000,40]

    char* w = (char*)d_ws;
    int*   deg      = (int*)w;    w += N_NODES * 4;
    float* colsum   = (float*)w;  w += 128 * 4;
    float* colsq    = (float*)w;  w += 128 * 4;
    // ---- end of memset-zero region: (N_NODES + 256) ints ----
    int*   eoff     = (int*)w;    w += N_EDGES * 4;
    int*   rowptr   = (int*)w;    w += 50004 * 4;
    float* norm     = (float*)w;  w += N_NODES * 4;
    float* norm2    = (float*)w;  w += N_NODES * 4;
    int*   blocksum = (int*)w;    w += 128 * 4;
    int*   csr      = (int*)w;    w += CSR_CAP * 4;
    // align row buffers to 256 B
    w = (char*)(((size_t)w + 255) & ~(size_t)255);
    const size_t HB = (size_t)(N_NODES + 1) * ROW_PAD * 4;   // padded rows + zero row
    uint*  fs       = (uint*)w;   w += HB;
    uint*  bufA     = (uint*)w;   w += HB;
    uint*  bufB     = (uint*)w;   w += HB;

    // 1. zero {deg, colsum, colsq} (one memset node)
    hipMemsetAsync(d_ws, 0, (size_t)(N_NODES + 256) * 4, stream);
    // 2. in-degree + per-edge slot (single atomic per edge total)
    deg_kernel<<<(N_EDGES + 255) / 256, 256, 0, stream>>>(dst, deg, eoff);
    // 3. rowptr over 8-aligned degrees + norm/norm2
    scan1_kernel<<<NSCAN_BLK, SCAN_B, 0, stream>>>(deg, rowptr, norm, norm2, blocksum);
    // 4. offsets + CSR pad slots (scan2+scan3 fused)
    scan23_kernel<<<NSCAN_BLK, SCAN_B, 0, stream>>>(rowptr, blocksum, deg, csr);
    // 5. CSR scatter + prescale + zero pad rows (fused)
    {
        int total = N_EDGES + N_NODES * 16 + 48;
        fill_kernel<<<(total + 255) / 256, 256, 0, stream>>>(
            src, dst, rowptr, eoff, csr, feat, norm,
            (uint4*)fs, (uint4*)bufA, (uint4*)bufB);
    }
    // 6. three hops: g1 = norm2*S(fs); g2 = norm2*S(g1); h3 = norm*S(g2)
    spmm_kernel<<<N_NODES / 2, 128, 0, stream>>>((const uint4*)fs, rowptr, csr, norm2, (uint4*)bufA);
    spmm_kernel<<<N_NODES / 2, 128, 0, stream>>>((const uint4*)bufA, rowptr, csr, norm2, (uint4*)bufB);
    spmm_kernel<<<N_NODES / 2, 128, 0, stream>>>((const uint4*)bufB, rowptr, csr, norm, (uint4*)bufA);
    // 7. column stats on padded bf16 h3
    col_stats_kernel<<<CS_BLOCKS, CS_THREADS, 0, stream>>>(bufA, colsum, colsq);
    // 8. final linear (prep fused; 10 threads per node)
    {
        int total = N_NODES * 10;
        final_kernel<<<(total + 255) / 256, 256, 0, stream>>>(
            (const uint4*)bufA, colsum, colsq, W, b, out);
    }
}

// Round 9
// 269.554 us; speedup vs baseline: 6.4263x; 1.0047x over previous
//
#include <hip/hip_runtime.h>
#include <hip/hip_fp16.h>

#define N_NODES 50000
#define N_EDGES 800000
#define IN_DIM 100
#define OUT_DIM 40
#define ROW 50            // 50 dwords = 100 fp16 per node row (used)
#define ROW_PAD 64        // padded pitch: 256 B -> one row = 16 lanes x dwordx4
#define SCAN_B 512
#define NSCAN_BLK ((N_NODES + SCAN_B - 1) / SCAN_B)   // 98
#define CSR_CAP (N_EDGES + N_NODES * 4 + 64)          // 4-aligned-degree worst case

typedef unsigned int uint;

// ---- fp16 pair helpers (packed in one dword) ----
__device__ __forceinline__ __half2 u2h(uint u) { union { uint u; __half2 h; } c; c.u = u; return c.h; }
__device__ __forceinline__ uint h2u(__half2 h) { union { uint u; __half2 h; } c; c.h = h; return c.u; }
__device__ __forceinline__ __half2 h2shfl_xor(__half2 v, int m) {
    float f = __uint_as_float(h2u(v));
    f = __shfl_xor(f, m);
    return u2h(__float_as_uint(f));
}

// ---------------- in-degree; keep returned old count as the edge's slot ----------------
__global__ void deg_kernel(const int* __restrict__ dst, int* __restrict__ deg,
                           int* __restrict__ eoff) {
    int e = blockIdx.x * blockDim.x + threadIdx.x;
    if (e < N_EDGES) eoff[e] = atomicAdd(&deg[dst[e]], 1);
}

// ---------------- scan phase 1: scan ALIGNED degrees ((d+3)&~3), emit norms ----
__global__ __launch_bounds__(SCAN_B) void scan1_kernel(const int* __restrict__ deg,
                                                       int* __restrict__ rowptr,
                                                       float* __restrict__ norm,
                                                       float* __restrict__ norm2,
                                                       int* __restrict__ blocksum) {
    int i = blockIdx.x * SCAN_B + threadIdx.x;
    int lane = threadIdx.x & 63, wid = threadIdx.x >> 6;
    int d = (i < N_NODES) ? deg[i] : 0;
    int da = (d + 3) & ~3;          // pad each node's edge list to multiple of 4
    int v = da;
#pragma unroll
    for (int off = 1; off < 64; off <<= 1) {
        int t = __shfl_up(v, off);
        if (lane >= off) v += t;
    }
    __shared__ int wsum[8];
    if (lane == 63) wsum[wid] = v;
    __syncthreads();
    if (threadIdx.x < 8) {
        int w = wsum[threadIdx.x];
#pragma unroll
        for (int off = 1; off < 8; off <<= 1) {
            int t = __shfl_up(w, off);
            if (lane >= off) w += t;
        }
        wsum[threadIdx.x] = w;
    }
    __syncthreads();
    int woff = wid ? wsum[wid - 1] : 0;
    int incl = woff + v;
    if (i < N_NODES) {
        rowptr[i] = incl - da;      // block-local exclusive
        float n1 = 1.0f / sqrtf((float)max(d, 1));
        norm[i] = n1;
        norm2[i] = n1 * n1;
    }
    if (threadIdx.x == SCAN_B - 1) blocksum[blockIdx.x] = incl;
}

// ---------------- scan phases 2+3 fused: offsets + CSR pad slots ----------------
__global__ __launch_bounds__(SCAN_B) void scan23_kernel(int* __restrict__ rowptr,
                                                        const int* __restrict__ blocksum,
                                                        const int* __restrict__ deg,
                                                        int* __restrict__ csr) {
    __shared__ int s_boff, s_tot;
    int t = threadIdx.x, bb = blockIdx.x;
    if (t == 0) {
        int boff = 0, tot = 0;
        for (int j = 0; j < NSCAN_BLK; ++j) {
            int v = blocksum[j];
            tot += v;
            if (j < bb) boff += v;
        }
        s_boff = boff;
        s_tot = tot;
    }
    __syncthreads();
    int i = bb * SCAN_B + t;
    if (i < N_NODES) {
        int rp = rowptr[i] + s_boff;
        rowptr[i] = rp;
        int d = deg[i], da = (d + 3) & ~3;
        for (int k = d; k < da; ++k) csr[rp + k] = N_NODES;   // dummy -> zero row
    }
    if (bb == 0 && t == 0) rowptr[N_NODES] = s_tot;
}

// ---------------- fused: CSR scatter + prescale(fp16) + zero pad rows ----------------
__global__ __launch_bounds__(256) void fill_kernel(const int* __restrict__ src,
                                                   const int* __restrict__ dst,
                                                   const int* __restrict__ rowptr,
                                                   const int* __restrict__ eoff,
                                                   int* __restrict__ csr,
                                                   const float* __restrict__ feat,
                                                   const float* __restrict__ norm,
                                                   uint4* __restrict__ fs4,
                                                   uint4* __restrict__ bufA4,
                                                   uint4* __restrict__ bufB4) {
    const int T1 = N_EDGES, T2 = N_NODES * 16;
    int task = blockIdx.x * 256 + threadIdx.x;
    if (task < T1) {
        csr[rowptr[dst[task]] + eoff[task]] = src[task];
    } else if (task < T1 + T2) {
        int qq = task - T1;
        int n = qq >> 4, ql = qq & 15;
        float nm = norm[n];
        uint4 o = make_uint4(0u, 0u, 0u, 0u);
        const float4* fr = (const float4*)(feat + (size_t)n * IN_DIM);
        if (ql < 12) {
            float4 a = fr[2 * ql], b2 = fr[2 * ql + 1];
            o.x = h2u(__floats2half2_rn(a.x * nm, a.y * nm));
            o.y = h2u(__floats2half2_rn(a.z * nm, a.w * nm));
            o.z = h2u(__floats2half2_rn(b2.x * nm, b2.y * nm));
            o.w = h2u(__floats2half2_rn(b2.z * nm, b2.w * nm));
        } else if (ql == 12) {
            float4 a = fr[24];                 // features 96..99
            o.x = h2u(__floats2half2_rn(a.x * nm, a.y * nm));
            o.y = h2u(__floats2half2_rn(a.z * nm, a.w * nm));
        }
        fs4[qq] = o;
    } else if (task < T1 + T2 + 48) {
        int k = task - T1 - T2;   // zero pad row (index N_NODES) of each buffer
        uint4 z = make_uint4(0u, 0u, 0u, 0u);
        uint4* dp = (k < 16) ? fs4 : (k < 32) ? bufA4 : bufB4;
        dp[(size_t)N_NODES * 16 + (k & 15)] = z;
    }
}

// ---------------- SGC hop: out[n] = fp16( scale[n] * sum_{s in N(n)} H[s] ) ----
// One wave per node (2 nodes / 128-thr block). Quarter-wave gather: each
// 16-lane quarter loads one full 256B row as dwordx4 -> 4 edges per load.
// Packed v_pk_add_f16 accumulation: 4 VALU adds per 4 edges (no unpack).
// Edge lists 4-aligned, dummies -> zero row: no bounds logic in the loop.
__global__ __launch_bounds__(128) void spmm_kernel(const uint4* __restrict__ H4,
                                                   const int* __restrict__ rowptr,
                                                   const int* __restrict__ csr,
                                                   const float* __restrict__ scale,
                                                   uint4* __restrict__ out4) {
    const int n = blockIdx.x * 2 + (threadIdx.x >> 6);
    const int l = threadIdx.x & 63;
    const int q = l >> 4;          // quarter 0..3
    const int ql = l & 15;         // lane within quarter
    const int beg = rowptr[n], end = rowptr[n + 1];   // multiple-of-4 span
    __half2 a0 = u2h(0u), a1 = u2h(0u), a2 = u2h(0u), a3 = u2h(0u);
#pragma unroll 4
    for (int j = beg; j < end; j += 4) {
        int s = csr[j + q];
        uint4 u = H4[(size_t)s * 16 + ql];
        a0 = __hadd2(a0, u2h(u.x));
        a1 = __hadd2(a1, u2h(u.y));
        a2 = __hadd2(a2, u2h(u.z));
        a3 = __hadd2(a3, u2h(u.w));
    }
    // reduce the 4 quarters
    a0 = __hadd2(a0, h2shfl_xor(a0, 16));
    a1 = __hadd2(a1, h2shfl_xor(a1, 16));
    a2 = __hadd2(a2, h2shfl_xor(a2, 16));
    a3 = __hadd2(a3, h2shfl_xor(a3, 16));
    a0 = __hadd2(a0, h2shfl_xor(a0, 32));
    a1 = __hadd2(a1, h2shfl_xor(a1, 32));
    a2 = __hadd2(a2, h2shfl_xor(a2, 32));
    a3 = __hadd2(a3, h2shfl_xor(a3, 32));
    if (q == 0) {
        float sc = scale[n];
        // scale in f32 for precision, repack to fp16
        float2 f0 = __half22float2(a0), f1 = __half22float2(a1);
        float2 f2 = __half22float2(a2), f3 = __half22float2(a3);
        uint4 o;
        o.x = h2u(__floats2half2_rn(f0.x * sc, f0.y * sc));
        o.y = h2u(__floats2half2_rn(f1.x * sc, f1.y * sc));
        o.z = h2u(__floats2half2_rn(f2.x * sc, f2.y * sc));
        o.w = h2u(__floats2half2_rn(f3.x * sc, f3.y * sc));
        out4[(size_t)n * 16 + ql] = o;   // full row incl. zero pads
    }
}

// ---------------- per-feature sum/sumsq over padded fp16 h3 ----------------
#define CS_BLOCKS 625
#define CS_THREADS 256   // stride 160000 (mult of 64) -> fixed dword-slot per thread
__global__ __launch_bounds__(CS_THREADS) void col_stats_kernel(const uint* __restrict__ h,
                                                               float* __restrict__ colsum,
                                                               float* __restrict__ colsq) {
    int gtid = blockIdx.x * CS_THREADS + threadIdx.x;
    const int stride = CS_BLOCKS * CS_THREADS;
    const int total = N_NODES * ROW_PAD;
    float s0 = 0.f, s1 = 0.f, q0 = 0.f, q1 = 0.f;
    for (int i = gtid; i < total; i += stride) {   // pads are zero, harmless
        float2 f = __half22float2(u2h(h[i]));
        s0 += f.x; s1 += f.y; q0 += f.x * f.x; q1 += f.y * f.y;
    }
    __shared__ float ssum[IN_DIM], ssq[IN_DIM];
    if (threadIdx.x < IN_DIM) { ssum[threadIdx.x] = 0.f; ssq[threadIdx.x] = 0.f; }
    __syncthreads();
    int p = gtid & 63;
    if (p < ROW) {
        atomicAdd(&ssum[2 * p], s0);
        atomicAdd(&ssum[2 * p + 1], s1);
        atomicAdd(&ssq[2 * p], q0);
        atomicAdd(&ssq[2 * p + 1], q1);
    }
    __syncthreads();
    if (threadIdx.x < IN_DIM) {
        atomicAdd(&colsum[threadIdx.x], ssum[threadIdx.x]);
        atomicAdd(&colsq[threadIdx.x], ssq[threadIdx.x]);
    }
}

// ---------------- final linear; rebuilds W'=W/sigma, b' in LDS (prep fused) ----
// sW padded to 104 features (rows 100..103 = 0) so the 13th uint4 of each row
// (dwords 48..51, features 96..103) needs no special-casing.
__global__ __launch_bounds__(256) void final_kernel(const uint4* __restrict__ h4,
                                                    const float* __restrict__ colsum,
                                                    const float* __restrict__ colsq,
                                                    const float* __restrict__ W,
                                                    const float* __restrict__ b,
                                                    float* __restrict__ out) {
    __shared__ float sW[104 * OUT_DIM];   // 16.25 KB
    __shared__ float sb[OUT_DIM];
    const float Nf = (float)N_NODES;
    for (int i = threadIdx.x; i < 104 * OUT_DIM; i += 256) {
        int f = i / OUT_DIM, o = i - f * OUT_DIM;
        float wv = 0.f;
        if (f < IN_DIM) {
            float m = colsum[f] / Nf;
            float var = fmaxf((colsq[f] - Nf * m * m) / (Nf - 1.0f), 1e-20f);
            wv = W[o * IN_DIM + f] * rsqrtf(var);
        }
        sW[i] = wv;
    }
    if (threadIdx.x < OUT_DIM) {
        float acc = b[threadIdx.x];
        for (int f = 0; f < IN_DIM; ++f) {
            float m = colsum[f] / Nf;
            float var = fmaxf((colsq[f] - Nf * m * m) / (Nf - 1.0f), 1e-20f);
            acc -= m * W[threadIdx.x * IN_DIM + f] * rsqrtf(var);
        }
        sb[threadIdx.x] = acc;
    }
    __syncthreads();
    int t = blockIdx.x * 256 + threadIdx.x;
    if (t >= N_NODES * 10) return;
    int n = t / 10;
    int og = (t - n * 10) * 4;            // output group of 4
    const uint4* hr = h4 + (size_t)n * 16;
    float a0 = sb[og], a1 = sb[og + 1], a2 = sb[og + 2], a3 = sb[og + 3];
#pragma unroll
    for (int r = 0; r < 13; ++r) {        // dwords 0..51 (50,51 are zero pads)
        uint4 u = hr[r];
        int f = r * 8;
        float2 p0 = __half22float2(u2h(u.x)), p1 = __half22float2(u2h(u.y));
        float2 p2 = __half22float2(u2h(u.z)), p3 = __half22float2(u2h(u.w));
        float v0 = p0.x, v1 = p0.y, v2 = p1.x, v3 = p1.y;
        float v4 = p2.x, v5 = p2.y, v6 = p3.x, v7 = p3.y;
        const float* w0 = &sW[(f + 0) * OUT_DIM + og];
        const float* w1 = &sW[(f + 1) * OUT_DIM + og];
        const float* w2 = &sW[(f + 2) * OUT_DIM + og];
        const float* w3 = &sW[(f + 3) * OUT_DIM + og];
        const float* w4 = &sW[(f + 4) * OUT_DIM + og];
        const float* w5 = &sW[(f + 5) * OUT_DIM + og];
        const float* w6 = &sW[(f + 6) * OUT_DIM + og];
        const float* w7 = &sW[(f + 7) * OUT_DIM + og];
        a0 += v0 * w0[0] + v1 * w1[0] + v2 * w2[0] + v3 * w3[0]
            + v4 * w4[0] + v5 * w5[0] + v6 * w6[0] + v7 * w7[0];
        a1 += v0 * w0[1] + v1 * w1[1] + v2 * w2[1] + v3 * w3[1]
            + v4 * w4[1] + v5 * w5[1] + v6 * w6[1] + v7 * w7[1];
        a2 += v0 * w0[2] + v1 * w1[2] + v2 * w2[2] + v3 * w3[2]
            + v4 * w4[2] + v5 * w5[2] + v6 * w6[2] + v7 * w7[2];
        a3 += v0 * w0[3] + v1 * w1[3] + v2 * w2[3] + v3 * w3[3]
            + v4 * w4[3] + v5 * w5[3] + v6 * w6[3] + v7 * w7[3];
    }
    float4 o = make_float4(a0, a1, a2, a3);
    *((float4*)(out + (size_t)n * OUT_DIM + og)) = o;
}

extern "C" void kernel_launch(void* const* d_in, const int* in_sizes, int n_in,
                              void* d_out, int out_size, void* d_ws, size_t ws_size,
                              hipStream_t stream) {
    const float* feat = (const float*)d_in[0];   // [50000,100]
    const float* W    = (const float*)d_in[1];   // [40,100]
    const float* b    = (const float*)d_in[2];   // [40]
    const int*   src  = (const int*)d_in[3];     // [800000]
    const int*   dst  = (const int*)d_in[4];     // [800000]
    float* out = (float*)d_out;                  // [50000,40]

    char* w = (char*)d_ws;
    int*   deg      = (int*)w;    w += N_NODES * 4;
    float* colsum   = (float*)w;  w += 128 * 4;
    float* colsq    = (float*)w;  w += 128 * 4;
    // ---- end of memset-zero region: (N_NODES + 256) ints ----
    int*   eoff     = (int*)w;    w += N_EDGES * 4;
    int*   rowptr   = (int*)w;    w += 50004 * 4;
    float* norm     = (float*)w;  w += N_NODES * 4;
    float* norm2    = (float*)w;  w += N_NODES * 4;
    int*   blocksum = (int*)w;    w += 128 * 4;
    int*   csr      = (int*)w;    w += CSR_CAP * 4;
    // align row buffers to 256 B
    w = (char*)(((size_t)w + 255) & ~(size_t)255);
    const size_t HB = (size_t)(N_NODES + 1) * ROW_PAD * 4;   // padded rows + zero row
    uint*  fs       = (uint*)w;   w += HB;
    uint*  bufA     = (uint*)w;   w += HB;
    uint*  bufB     = (uint*)w;   w += HB;

    // 1. zero {deg, colsum, colsq} (one memset node)
    hipMemsetAsync(d_ws, 0, (size_t)(N_NODES + 256) * 4, stream);
    // 2. in-degree + per-edge slot (single atomic per edge total)
    deg_kernel<<<(N_EDGES + 255) / 256, 256, 0, stream>>>(dst, deg, eoff);
    // 3. rowptr over 4-aligned degrees + norm/norm2
    scan1_kernel<<<NSCAN_BLK, SCAN_B, 0, stream>>>(deg, rowptr, norm, norm2, blocksum);
    // 4. offsets + CSR pad slots (scan2+scan3 fused)
    scan23_kernel<<<NSCAN_BLK, SCAN_B, 0, stream>>>(rowptr, blocksum, deg, csr);
    // 5. CSR scatter + prescale + zero pad rows (fused)
    {
        int total = N_EDGES + N_NODES * 16 + 48;
        fill_kernel<<<(total + 255) / 256, 256, 0, stream>>>(
            src, dst, rowptr, eoff, csr, feat, norm,
            (uint4*)fs, (uint4*)bufA, (uint4*)bufB);
    }
    // 6. three hops: g1 = norm2*S(fs); g2 = norm2*S(g1); h3 = norm*S(g2)
    spmm_kernel<<<N_NODES / 2, 128, 0, stream>>>((const uint4*)fs, rowptr, csr, norm2, (uint4*)bufA);
    spmm_kernel<<<N_NODES / 2, 128, 0, stream>>>((const uint4*)bufA, rowptr, csr, norm2, (uint4*)bufB);
    spmm_kernel<<<N_NODES / 2, 128, 0, stream>>>((const uint4*)bufB, rowptr, csr, norm, (uint4*)bufA);
    // 7. column stats on padded fp16 h3
    col_stats_kernel<<<CS_BLOCKS, CS_THREADS, 0, stream>>>(bufA, colsum, colsq);
    // 8. final linear (prep fused; 10 threads per node)
    {
        int total = N_NODES * 10;
        final_kernel<<<(total + 255) / 256, 256, 0, stream>>>(
            (const uint4*)bufA, colsum, colsq, W, b, out);
    }
}